// Round 11
// baseline (399.737 us; speedup 1.0000x reference)
//
#include <hip/hip_runtime.h>
#include <stdint.h>
#include <math.h>

typedef __bf16 bf16;
typedef __bf16 bf16x8 __attribute__((ext_vector_type(8)));
typedef __bf16 bf16x4 __attribute__((ext_vector_type(4)));
typedef float  f32x4  __attribute__((ext_vector_type(4)));

#define NVALID 2080            // D*(D+1)/2 valid (h<=w) pixels
#define NCOLS  16640           // B*NVALID  (bm rows, n-dim)
#define KDIM   4096            // NS*C2D    (bm cols, k = s*128+c)

// ws layout (bytes)
#define OFF_XBT   0u           // bf16 [8][256][128] = 512 KB
#define OFF_W3B   524288u      // bf16 [512][4096] (k=s*128+c) = 4 MB
#define OFF_W2B   4718592u     // bf16 [128][512]
#define OFF_CVEC  4849664u     // f32  [128]
#define OFF_PIX   4850176u     // int  [2080]
#define OFF_W1K   4859904u     // bf16 [768][128] = 196,608 (ends 5,056,512)
#define OFF_TABW  5253120u     // f32  [2080][32][8] = 2,129,920
#define OFF_TABT  7383040u     // u8   [2080][32][8] = 532,480 (ends 7,915,520)
#define OFF_X3    8388608u     // bf16 [16640][512] = 17,039,360 (ends 25,427,968)
#define OFF_BASET 25427968u    // bf16 [8][258][256] = 1,056,768 (ends 26,484,736)
#define OFF_P4A   26484736u    // bf16 [128][16640] = 4,259,840 (ends 30,744,576)
#define OFF_P4B   30744576u    // bf16 [128][16640] = 4,259,840 (ends 35,004,416)
#define OFF_BM    42991616u    // bf16 [16640][4096] = 136 MB (ends 179,306,496)

__device__ __forceinline__ void gload_lds16(const void* g, void* l) {
    __builtin_amdgcn_global_load_lds(
        (const __attribute__((address_space(1))) void*)g,
        (__attribute__((address_space(3))) void*)l, 16, 0, 0);
}

// Stage 16 rows x 32 k (bf16) into LDS with XOR swizzle.
__device__ __forceinline__ void stage16(const bf16* gbase, int stride, int rbase,
                                        int k0, bf16* ldsbase, int lane) {
    int row = rbase + (lane >> 2);
    int cg  = (lane & 3) ^ ((row >> 1) & 3);
    gload_lds16(gbase + (size_t)row * stride + k0 + cg * 8, ldsbase + rbase * 32);
}

__device__ __forceinline__ bf16x8 fragld(const bf16* lds, int row, int q) {
    int c = q ^ ((row >> 1) & 3);
    return *(const bf16x8*)(lds + row * 32 + c * 8);
}

// ---------------- misc mega-kernel ------------------------------------------
// grid 885: 0 = cvec+pix2hw; 1..16 = w2 cast; 17..528 = w3 transpose;
//           529..624 = w1 -> w1kb[k=j*256+ci][co]; 625..884 = sample table
__global__ __launch_bounds__(256) void k_misc(const float* __restrict__ w1,
                                              const float* __restrict__ w2,
                                              const float* __restrict__ b2,
                                              const float* __restrict__ b3,
                                              const float* __restrict__ w3,
                                              bf16* __restrict__ w1kb,
                                              bf16* __restrict__ w2b,
                                              bf16* __restrict__ w3b,
                                              float* __restrict__ cvec,
                                              int* __restrict__ pix2hw,
                                              float* __restrict__ tabw,
                                              uint8_t* __restrict__ tabt) {
    int tid = threadIdx.x, bx = blockIdx.x;
    if (bx == 0) {
        int wv = tid >> 6, ln = tid & 63;
        for (int c = wv; c < 128; c += 4) {
            const float* row = w2 + (size_t)c * 512 + ln * 8;
            float p = 0.f;
            #pragma unroll
            for (int k = 0; k < 8; k++) {
                float r = b3[ln * 8 + k]; r = r > 0.f ? r : 0.f;
                p += row[k] * r;
            }
            #pragma unroll
            for (int off = 32; off; off >>= 1) p += __shfl_down(p, off);
            if (ln == 0) {
                p += b2[c];
                cvec[c] = p > 0.f ? p : 0.f;
            }
        }
        for (int pix = tid; pix < NVALID; pix += 256) {
            int h = 0, base = 0;
            while (pix >= base + (64 - h)) { base += 64 - h; h++; }
            int w = h + (pix - base);
            pix2hw[pix] = h * 64 + w;
        }
    } else if (bx <= 16) {
        int i = ((bx - 1) * 256 + tid) * 16;
        #pragma unroll
        for (int j = 0; j < 16; j++) w2b[i + j] = (bf16)w2[i + j];
    } else if (bx <= 528) {
        // transpose one o row: w3[o][c][s] -> w3b[o][s*128+c]
        __shared__ float l[128 * 33];
        int o = bx - 17;
        const float* src = w3 + (size_t)o * 4096;
        #pragma unroll
        for (int m = 0; m < 16; m++) {
            int i = m * 256 + tid;
            int c = i >> 5, s = i & 31;
            l[c * 33 + s] = src[i];
        }
        __syncthreads();
        bf16* d = w3b + (size_t)o * 4096;
        #pragma unroll
        for (int m = 0; m < 16; m++) {
            int k = m * 256 + tid;
            int s = k >> 7, c = k & 127;
            d[k] = (bf16)l[c * 33 + s];
        }
    } else if (bx <= 624) {
        // w1[co][ci][j] -> w1kb[(j*256+ci)*128 + co]; 96 blocks x 1024 elems
        int e0 = (bx - 529) * 1024 + tid * 4;
        #pragma unroll
        for (int m = 0; m < 4; m++) {
            int e = e0 + m;              // global w1kb flat index
            int k = e >> 7, co = e & 127;
            int ci = k & 255, j = k >> 8;
            w1kb[e] = (bf16)w1[(size_t)co * 768 + ci * 3 + j];
        }
    } else {
        // sample table: per (pix,s) 6 (t, weight) pairs, double-exact
        int idx = (bx - 625) * 256 + tid;   // p*32+s
        if (idx >= NVALID * 32) return;
        int p = idx >> 5, s = idx & 31;
        int h = 0, base = 0;
        while (p >= base + (64 - h)) { base += 64 - h; h++; }
        int w = h + (p - base);
        double sp = 4.0 * h, ep = 4.0 * (w + 1);
        double L = ep - sp + 1.0;
        double start_p = sp - L * 0.5;
        double end_p   = ep + L * 0.5;
        double step = (end_p - start_p) / 95.0;
        float*   wd = tabw + (size_t)idx * 8;
        uint8_t* td = tabt + (size_t)idx * 8;
        #pragma unroll
        for (int i = 0; i < 3; i++) {
            double pos = start_p + step * (3 * s + i);
            double tr = trunc(pos);
            double fr = pos - tr;
            int it = (int)tr;
            bool ok = (it >= 0 && it < 255);
            wd[i*2+0] = ok ? (float)((1.0 - fr) / 3.0) : 0.f;
            td[i*2+0] = (uint8_t)(ok ? it : 0);
            wd[i*2+1] = ok ? (float)(fr / 3.0) : 0.f;
            td[i*2+1] = (uint8_t)(ok ? it + 1 : 0);
        }
        wd[6] = 0.f; wd[7] = 0.f; td[6] = 0; td[7] = 0;
    }
}

// ---------------- transpose+cast: base[b][ci][t] -> baseT[b][1+t][ci] bf16 ---
// grid 129: blocks 0..127 do 64x64 tiles; block 128 zeroes pad rows 0 & 257.
__global__ __launch_bounds__(256) void k_tr(const float* __restrict__ base,
                                            bf16* __restrict__ baseT) {
    int tid = threadIdx.x;
    if (blockIdx.x == 128) {
        for (int k = tid; k < 8 * 2 * 256; k += 256) {
            int b = k >> 9, rr = (k >> 8) & 1, ci = k & 255;
            baseT[((size_t)b * 258 + rr * 257) * 256 + ci] = (bf16)0.f;
        }
        return;
    }
    __shared__ float l[64][65];
    int id = blockIdx.x;
    int b = id >> 4, ci0 = ((id >> 2) & 3) * 64, t0 = (id & 3) * 64;
    #pragma unroll
    for (int m = 0; m < 16; m++) {
        int idx = m * 256 + tid;
        int ci_l = idx >> 6, t_l = idx & 63;
        l[ci_l][t_l] = base[((size_t)b * 256 + ci0 + ci_l) * 256 + t0 + t_l];
    }
    __syncthreads();
    #pragma unroll
    for (int m = 0; m < 16; m++) {
        int idx = m * 256 + tid;
        int t_l = idx >> 6, ci_l = idx & 63;
        baseT[((size_t)b * 258 + 1 + t0 + t_l) * 256 + ci0 + ci_l] = (bf16)l[ci_l][t_l];
    }
}

// ---------------- conv as VALU GEMV: xbT[b][t][co] = relu(A . w1kb + b1) -----
// grid 512 (b, t-quad); wave = one t; lane covers co = {2*lane, 2*lane+1}.
// A-row (768 bf16, halo window) broadcast from LDS; W loads coalesced 256 B.
__global__ __launch_bounds__(256) void k_conv2(const bf16* __restrict__ baseT,
                                               const bf16* __restrict__ w1kb,
                                               const float* __restrict__ b1,
                                               bf16* __restrict__ xbT) {
    __shared__ __align__(16) bf16 al[6 * 256];
    int tid = threadIdx.x, lane = tid & 63, wave = tid >> 6;
    int bx = blockIdx.x;
    int b = bx >> 6, t0 = (bx & 63) * 4;
    if (tid < 192)
        *(uint4*)((char*)al + tid * 16) =
            *(const uint4*)((const char*)(baseT + ((size_t)b * 258 + t0) * 256) + tid * 16);
    __syncthreads();
    int t = t0 + wave;
    const bf16* arow = al + wave * 256;       // A[k], k in [0,768)
    float acc0 = b1[lane * 2], acc1 = b1[lane * 2 + 1];
    const uint32_t* wp = (const uint32_t*)w1kb;   // [768][64] uints (co pairs)
    for (int k8 = 0; k8 < 768; k8 += 8) {
        bf16x8 av = *(const bf16x8*)(arow + k8);
        #pragma unroll
        for (int u = 0; u < 8; u++) {
            float a = (float)av[u];
            uint32_t x = wp[(k8 + u) * 64 + lane];
            union { uint32_t u_; float f; } lo, hi;
            lo.u_ = x << 16; hi.u_ = x & 0xffff0000u;
            acc0 += a * lo.f;
            acc1 += a * hi.f;
        }
    }
    acc0 = acc0 > 0.f ? acc0 : 0.f;
    acc1 = acc1 > 0.f ? acc1 : 0.f;
    union { uint32_t u; bf16 h[2]; } o;
    o.h[0] = (bf16)acc0; o.h[1] = (bf16)acc1;
    *(uint32_t*)(xbT + ((size_t)b * 256 + t) * 128 + lane * 2) = o.u;
}

// ---------------- bm sparse (R8-proven): one wave per bm row -----------------
__global__ __launch_bounds__(256) void k_bm(const bf16* __restrict__ xbT,
                                            const float* __restrict__ tabw,
                                            const uint8_t* __restrict__ tabt,
                                            bf16* __restrict__ bm) {
    int lane = threadIdx.x & 63;
    int n = __builtin_amdgcn_readfirstlane(blockIdx.x * 4 + (threadIdx.x >> 6));
    int b = n / NVALID, p = n - b * NVALID;
    const bf16* xs = xbT + (size_t)b * 32768;
    bf16* dst = bm + (size_t)n * (size_t)KDIM;
    for (int s = 0; s < 32; s++) {
        const float*   wv = tabw + (size_t)(p * 32 + s) * 8;
        const uint8_t* tv = tabt + (size_t)(p * 32 + s) * 8;
        float a0 = 0.f, a1 = 0.f;
        #pragma unroll
        for (int j = 0; j < 6; j++) {
            float w = wv[j];
            int   t = tv[j];
            uint32_t x = *(const uint32_t*)(xs + t * 128 + lane * 2);
            union { uint32_t u; float f; } lo, hi;
            lo.u = x << 16;
            hi.u = x & 0xffff0000u;
            a0 += w * lo.f;
            a1 += w * hi.f;
        }
        union { uint32_t u; bf16 h[2]; } o;
        o.h[0] = (bf16)a0; o.h[1] = (bf16)a1;
        *(uint32_t*)(dst + s * 128 + lane * 2) = o.u;
    }
}

// ---------------- GEMM3 (proven): x3[n][o] = relu(w3b @ bm^T + b3) -----------
__global__ __launch_bounds__(256, 2) void k_gemm3f(const bf16* __restrict__ w3b,
                                                   const bf16* __restrict__ bm,
                                                   const float* __restrict__ b3,
                                                   bf16* __restrict__ x3) {
    __shared__ __align__(16) char lds[34816];
    bf16* As0 = (bf16*)lds;
    bf16* Bs0 = (bf16*)(lds + 16384);
    bf16* T2  = (bf16*)lds;

    int tid = threadIdx.x, lane = tid & 63, wave = tid >> 6;
    int m16 = lane & 15, q = lane >> 4;
    int wm = wave >> 1, wn = wave & 1;
    int id = blockIdx.x, nt, ot;
    if (id >= 512) { int r = id - 512; nt = 128 + (r & 1); ot = r >> 1; }
    else           { nt = (id >> 5) * 8 + (id & 7); ot = (id >> 3) & 3; }
    int n0 = nt * 128, o0 = ot * 128;
    const bf16* Ag = w3b + (size_t)o0 * KDIM;
    const bf16* Bg = bm + (size_t)n0 * KDIM;

    f32x4 acc[4][4];
    #pragma unroll
    for (int i = 0; i < 4; i++)
        #pragma unroll
        for (int j = 0; j < 4; j++) acc[i][j] = (f32x4){0.f, 0.f, 0.f, 0.f};

    stage16(Ag, KDIM, wave * 32,      0, As0, lane);
    stage16(Ag, KDIM, wave * 32 + 16, 0, As0, lane);
    stage16(Bg, KDIM, wave * 32,      0, Bs0, lane);
    stage16(Bg, KDIM, wave * 32 + 16, 0, Bs0, lane);

    for (int ks = 0; ks < 128; ks++) {
        __syncthreads();
        if (ks < 127) {
            int k0 = (ks + 1) * 32, o = ((ks + 1) & 1) * 4096;
            stage16(Ag, KDIM, wave * 32,      k0, As0 + o, lane);
            stage16(Ag, KDIM, wave * 32 + 16, k0, As0 + o, lane);
            stage16(Bg, KDIM, wave * 32,      k0, Bs0 + o, lane);
            stage16(Bg, KDIM, wave * 32 + 16, k0, Bs0 + o, lane);
        }
        const bf16* Ac = As0 + (ks & 1) * 4096;
        const bf16* Bc = Bs0 + (ks & 1) * 4096;
        bf16x8 af[4], bfv[4];
        #pragma unroll
        for (int i = 0; i < 4; i++) af[i]  = fragld(Ac, wm * 64 + i * 16 + m16, q);
        #pragma unroll
        for (int j = 0; j < 4; j++) bfv[j] = fragld(Bc, wn * 64 + j * 16 + m16, q);
        #pragma unroll
        for (int i = 0; i < 4; i++)
            #pragma unroll
            for (int j = 0; j < 4; j++)
                acc[i][j] = __builtin_amdgcn_mfma_f32_16x16x32_bf16(af[i], bfv[j], acc[i][j], 0, 0, 0);
    }
    __syncthreads();
    #pragma unroll
    for (int i = 0; i < 4; i++)
        #pragma unroll
        for (int r = 0; r < 4; r++) {
            int o_l = wm * 64 + i * 16 + q * 4 + r;
            float bias = b3[o0 + o_l];
            #pragma unroll
            for (int j = 0; j < 4; j++) {
                int n_l = wn * 64 + j * 16 + m16;
                float v = acc[i][j][r] + bias; v = v > 0.f ? v : 0.f;
                T2[n_l * 136 + o_l] = (bf16)v;
            }
        }
    __syncthreads();
    {
        int n_l = tid >> 1, half = (tid & 1) * 64;
        bf16* dst = x3 + (size_t)(n0 + n_l) * 512 + o0 + half;
        const bf16* src = T2 + n_l * 136 + half;
        #pragma unroll
        for (int m = 0; m < 8; m++)
            *(bf16x8*)(dst + m * 8) = *(const bf16x8*)(src + m * 8);
    }
}

// ---------------- GEMM4 split-K x2: partial[o2][n] bf16 ----------------------
// grid 520: kt = id&1, nt = id>>1; tile 128 o2 x 64 n, K=256 (8 iters).
__global__ __launch_bounds__(256, 4) void k_gemm4s(const bf16* __restrict__ w2b,
                                                   const bf16* __restrict__ x3,
                                                   bf16* __restrict__ pa,
                                                   bf16* __restrict__ pb) {
    __shared__ __align__(16) char lds[24576];
    bf16* As0 = (bf16*)lds;              // [2][128][32]
    bf16* Bs0 = (bf16*)(lds + 16384);    // [2][64][32]
    bf16* T2  = (bf16*)lds;              // [128][72] epilogue (18 KB, aliases)

    int tid = threadIdx.x, lane = tid & 63, wave = tid >> 6;
    int m16 = lane & 15, q = lane >> 4;
    int kt = blockIdx.x & 1, nt = blockIdx.x >> 1;
    int n0 = nt * 64;
    const bf16* Ag = w2b + kt * 256;
    const bf16* Bg = x3 + (size_t)n0 * 512 + kt * 256;
    bf16* part = kt ? pb : pa;

    f32x4 acc[2][4];
    #pragma unroll
    for (int i = 0; i < 2; i++)
        #pragma unroll
        for (int j = 0; j < 4; j++) acc[i][j] = (f32x4){0.f, 0.f, 0.f, 0.f};

    stage16(Ag, 512, wave * 32,      0, As0, lane);
    stage16(Ag, 512, wave * 32 + 16, 0, As0, lane);
    stage16(Bg, 512, wave * 16,      0, Bs0, lane);

    for (int ks = 0; ks < 8; ks++) {
        __syncthreads();
        if (ks < 7) {
            int k0 = (ks + 1) * 32, oA = ((ks + 1) & 1) * 4096, oB = ((ks + 1) & 1) * 2048;
            stage16(Ag, 512, wave * 32,      k0, As0 + oA, lane);
            stage16(Ag, 512, wave * 32 + 16, k0, As0 + oA, lane);
            stage16(Bg, 512, wave * 16,      k0, Bs0 + oB, lane);
        }
        const bf16* Ac = As0 + (ks & 1) * 4096;
        const bf16* Bc = Bs0 + (ks & 1) * 2048;
        bf16x8 af[2], bfv[4];
        #pragma unroll
        for (int i = 0; i < 2; i++) af[i]  = fragld(Ac, wave * 32 + i * 16 + m16, q);
        #pragma unroll
        for (int j = 0; j < 4; j++) bfv[j] = fragld(Bc, j * 16 + m16, q);
        #pragma unroll
        for (int i = 0; i < 2; i++)
            #pragma unroll
            for (int j = 0; j < 4; j++)
                acc[i][j] = __builtin_amdgcn_mfma_f32_16x16x32_bf16(af[i], bfv[j], acc[i][j], 0, 0, 0);
    }
    __syncthreads();
    #pragma unroll
    for (int i = 0; i < 2; i++)
        #pragma unroll
        for (int r = 0; r < 4; r++) {
            int o_l = wave * 32 + i * 16 + q * 4 + r;
            #pragma unroll
            for (int j = 0; j < 4; j++) {
                int n_l = j * 16 + m16;
                T2[o_l * 72 + n_l] = (bf16)acc[i][j][r];
            }
        }
    __syncthreads();
    {
        int o2 = tid >> 1, half = (tid & 1) * 32;
        bf16* dst = part + (size_t)o2 * NCOLS + n0 + half;
        const bf16* src = T2 + o2 * 72 + half;
        #pragma unroll
        for (int m = 0; m < 8; m++)
            *(bf16x4*)(dst + m * 4) = *(const bf16x4*)(src + m * 4);
    }
}

// ---------------- combine + fill ---------------------------------------------
// blocks [0,260): out = relu(pa+pb+b2) scattered; [260,1284): triangular fill
__global__ __launch_bounds__(256) void k_comb4(const bf16* __restrict__ pa,
                                               const bf16* __restrict__ pb,
                                               const float* __restrict__ b2,
                                               const int* __restrict__ pix2hw,
                                               const float* __restrict__ cvec,
                                               float* __restrict__ out) {
    int tid = threadIdx.x, bx = blockIdx.x;
    if (bx >= 260) {
        int bo = bx - 260;                 // b*128 + o2
        float v = cvec[bo & 127];
        float* dst = out + (size_t)bo * 4096;
        for (int hw = tid; hw < 4096; hw += 256) {
            int h = hw >> 6, w = hw & 63;
            if (w < h) dst[hw] = v;
        }
        return;
    }
    int n0 = bx * 64;
    int n_l = (tid & 31) * 2, oq = tid >> 5;
    int n = n0 + n_l;
    int b0_ = n / NVALID, p0_ = n - b0_ * NVALID;
    int n1 = n + 1;
    int b1_ = n1 / NVALID, p1_ = n1 - b1_ * NVALID;
    int hw0 = pix2hw[p0_], hw1 = pix2hw[p1_];
    #pragma unroll
    for (int it = 0; it < 16; it++) {
        int o2 = it * 8 + oq;
        uint32_t a = *(const uint32_t*)(pa + (size_t)o2 * NCOLS + n);
        uint32_t c = *(const uint32_t*)(pb + (size_t)o2 * NCOLS + n);
        float bias = b2[o2];
        union { uint32_t u; float f; } al, ah, cl, ch;
        al.u = a << 16; ah.u = a & 0xffff0000u;
        cl.u = c << 16; ch.u = c & 0xffff0000u;
        float v0 = al.f + cl.f + bias; v0 = v0 > 0.f ? v0 : 0.f;
        float v1 = ah.f + ch.f + bias; v1 = v1 > 0.f ? v1 : 0.f;
        out[(size_t)b0_ * 524288 + o2 * 4096 + hw0] = v0;
        out[(size_t)b1_ * 524288 + o2 * 4096 + hw1] = v1;
    }
}

extern "C" void kernel_launch(void* const* d_in, const int* in_sizes, int n_in,
                              void* d_out, int out_size, void* d_ws, size_t ws_size,
                              hipStream_t stream) {
    const float* base = (const float*)d_in[0];
    const float* w1   = (const float*)d_in[1];
    const float* b1   = (const float*)d_in[2];
    const float* w3   = (const float*)d_in[3];
    const float* b3   = (const float*)d_in[4];
    const float* w2   = (const float*)d_in[5];
    const float* b2   = (const float*)d_in[6];
    float* out = (float*)d_out;
    char* ws = (char*)d_ws;
    bf16*    xbT    = (bf16*)(ws + OFF_XBT);
    bf16*    w3b    = (bf16*)(ws + OFF_W3B);
    bf16*    w2b    = (bf16*)(ws + OFF_W2B);
    float*   cvec   = (float*)(ws + OFF_CVEC);
    int*     pix2hw = (int*)(ws + OFF_PIX);
    bf16*    w1kb   = (bf16*)(ws + OFF_W1K);
    float*   tabw   = (float*)(ws + OFF_TABW);
    uint8_t* tabt   = (uint8_t*)(ws + OFF_TABT);
    bf16*    x3     = (bf16*)(ws + OFF_X3);
    bf16*    baseT  = (bf16*)(ws + OFF_BASET);
    bf16*    p4a    = (bf16*)(ws + OFF_P4A);
    bf16*    p4b    = (bf16*)(ws + OFF_P4B);
    bf16*    bm     = (bf16*)(ws + OFF_BM);

    k_misc<<<dim3(885), dim3(256), 0, stream>>>(w1, w2, b2, b3, w3, w1kb, w2b, w3b,
                                                cvec, pix2hw, tabw, tabt);
    k_tr<<<dim3(129), dim3(256), 0, stream>>>(base, baseT);
    k_conv2<<<dim3(512), dim3(256), 0, stream>>>(baseT, w1kb, b1, xbT);
    k_bm<<<dim3(4160), dim3(256), 0, stream>>>(xbT, tabw, tabt, bm);
    k_gemm3f<<<dim3(520), dim3(256), 0, stream>>>(w3b, bm, b3, x3);
    k_gemm4s<<<dim3(520), dim3(256), 0, stream>>>(w2b, x3, p4a, p4b);
    k_comb4<<<dim3(1284), dim3(256), 0, stream>>>(p4a, p4b, b2, pix2hw, cvec, out);
}